// Round 7
// baseline (181.367 us; speedup 1.0000x reference)
//
#include <hip/hip_runtime.h>
#include <stdint.h>
#include <stddef.h>

#define SEQ 4096
#define DM 1024
#define DH 128
#define NB 4
#define SPLITS 4

typedef __attribute__((ext_vector_type(8))) short bf16x8;
typedef __attribute__((ext_vector_type(4))) float f32x4;

__device__ __forceinline__ unsigned short f2bf(float f) {
    union { float f; uint32_t u; } v; v.f = f;
    uint32_t u = v.u + 0x7FFF + ((v.u >> 16) & 1);   // round-to-nearest-even
    return (unsigned short)(u >> 16);
}

// packed f32x2 -> bf16x2 (RNE), src0 in low half. No builtin on gfx950.
__device__ __forceinline__ uint32_t cvt_pk_bf16(float lo, float hi) {
    uint32_t r;
    asm("v_cvt_pk_bf16_f32 %0, %1, %2" : "=v"(r) : "v"(lo), "v"(hi));
    return r;
}

__device__ __forceinline__ void gload_lds16(const void* g, void* l) {
    __builtin_amdgcn_global_load_lds(
        (const __attribute__((address_space(1))) void*)g,
        (__attribute__((address_space(3))) void*)l, 16, 0, 0);
}

// ---------------------------------------------------------------------------
// prep: build Wt[384][1024] = concat(Wq,Wk,Wv)^T bf16. Wq pre-scaled 1/sqrt(DH).
// ---------------------------------------------------------------------------
__global__ __launch_bounds__(256) void prep_kernel(
    const float* __restrict__ Wq, const float* __restrict__ Wk,
    const float* __restrict__ Wv, unsigned short* __restrict__ Wt)
{
    int idx = blockIdx.x * 256 + threadIdx.x;       // [0, 393216)
    int n = idx >> 10, k = idx & 1023;              // n in [0,384), k in [0,1024)
    int p = n >> 7, c = n & 127;
    const float* W = (p == 0) ? Wq : (p == 1) ? Wk : Wv;
    float v = W[k * DH + c];
    if (p == 0) v *= 0.08838834764831845f;          // 1/sqrt(128)
    Wt[idx] = f2bf(v);
}

// ---------------------------------------------------------------------------
// proj (FUSED q|k|v): C[16384,384] = x[16384,1024] @ Wt^T. BM=64, BN=192
// (N split in 2 -> grid 512 = 2 blocks/CU for block-level TLP while one
// block sits in its barrier drain). 512 threads = 8 waves (2m x 4n), wave
// owns 32x48. x read with cvt_pk fp32->bf16 on the fly. Double-buffered
// LDS (68KB -> 2 blocks/CU), ONE barrier per k-step, DMA issued early.
// ---------------------------------------------------------------------------
__global__ __launch_bounds__(512) void proj_kernel(
    const float* __restrict__ x,             // [16384][1024] fp32
    const unsigned short* __restrict__ Wt,   // [384][1024] bf16
    const float* __restrict__ bq, const float* __restrict__ bk,
    const float* __restrict__ bv,
    unsigned short* __restrict__ qb, unsigned short* __restrict__ kb,
    unsigned short* __restrict__ vt)         // [4][128][4096]
{
    __shared__ unsigned short A_lds[2][64 * 72];    // padded rows
    __shared__ unsigned short B_lds[2][192 * 64];   // linear, src-swizzled
    const int tid = threadIdx.x;
    const int lane = tid & 63, w = tid >> 6;
    const int wm = w >> 2, wn = w & 3;              // wave grid 2m x 4n
    const int q15 = lane & 15, g = lane >> 4;
    const int mt = blockIdx.x >> 1;                 // [0,256): 64-row M tile
    const int nt = blockIdx.x & 1;                  // N half
    const int nbase = nt * 192;

    const int arow = tid >> 3, aseg = tid & 7;      // 64 rows x 8 segs = 512

    f32x4 acc[2][3];
    #pragma unroll
    for (int mi = 0; mi < 2; ++mi)
        #pragma unroll
        for (int ni = 0; ni < 3; ++ni) acc[mi][ni] = (f32x4){0.f, 0.f, 0.f, 0.f};

    const float* asrc = x + (size_t)(mt * 64 + arow) * DM + aseg * 8;
    const unsigned short* bsrc = Wt + (size_t)nbase * DM;

    // ---- prologue: stage kt=0 into buffer 0 ----
    #pragma unroll
    for (int t = 0; t < 3; ++t) {
        int brow = t * 64 + arow;
        int bl = aseg ^ (brow & 7);                 // logical seg for this slot
        gload_lds16(bsrc + (size_t)brow * DM + bl * 8,
                    (char*)&B_lds[0][0] + t * 8192 + tid * 16);
    }
    {
        f32x4 lo4 = *(const f32x4*)asrc;
        f32x4 hi4 = *(const f32x4*)(asrc + 4);
        uint32_t* ad = (uint32_t*)&A_lds[0][arow * 72 + aseg * 8];
        ad[0] = cvt_pk_bf16(lo4[0], lo4[1]);
        ad[1] = cvt_pk_bf16(lo4[2], lo4[3]);
        ad[2] = cvt_pk_bf16(hi4[0], hi4[1]);
        ad[3] = cvt_pk_bf16(hi4[2], hi4[3]);
    }
    __syncthreads();

    int cur = 0;
    for (int kt = 0; kt < 16; ++kt) {
        f32x4 nlo, nhi;
        if (kt < 15) {
            // issue next B DMA (latency hides under MFMA below)
            #pragma unroll
            for (int t = 0; t < 3; ++t) {
                int brow = t * 64 + arow;
                int bl = aseg ^ (brow & 7);
                gload_lds16(bsrc + (size_t)brow * DM + (kt + 1) * 64 + bl * 8,
                            (char*)&B_lds[cur ^ 1][0] + t * 8192 + tid * 16);
            }
            // issue next A fp32 loads
            nlo = *(const f32x4*)(asrc + (kt + 1) * 64);
            nhi = *(const f32x4*)(asrc + (kt + 1) * 64 + 4);
        }
        // ---- MFMA on current buffer ----
        #pragma unroll
        for (int kk = 0; kk < 2; ++kk) {
            bf16x8 af[2], bfr[3];
            #pragma unroll
            for (int mi = 0; mi < 2; ++mi)
                af[mi] = *(const bf16x8*)&A_lds[cur][(wm * 32 + mi * 16 + q15) * 72 + (kk * 4 + g) * 8];
            #pragma unroll
            for (int ni = 0; ni < 3; ++ni)
                bfr[ni] = *(const bf16x8*)&B_lds[cur][(wn * 48 + ni * 16 + q15) * 64 + ((kk * 4 + g) ^ (q15 & 7)) * 8];
            #pragma unroll
            for (int mi = 0; mi < 2; ++mi)
                #pragma unroll
                for (int ni = 0; ni < 3; ++ni)
                    acc[mi][ni] = __builtin_amdgcn_mfma_f32_16x16x32_bf16(
                        af[mi], bfr[ni], acc[mi][ni], 0, 0, 0);
        }
        if (kt < 15) {
            // convert + commit next A into the other buffer
            uint32_t* ad = (uint32_t*)&A_lds[cur ^ 1][arow * 72 + aseg * 8];
            ad[0] = cvt_pk_bf16(nlo[0], nlo[1]);
            ad[1] = cvt_pk_bf16(nlo[2], nlo[3]);
            ad[2] = cvt_pk_bf16(nhi[0], nhi[1]);
            ad[3] = cvt_pk_bf16(nhi[2], nhi[3]);
        }
        __syncthreads();
        cur ^= 1;
    }

    // ---- epilogue: +bias, cast bf16, store (q,k row-major; v transposed) ----
    #pragma unroll
    for (int ni = 0; ni < 3; ++ni) {
        int n = nbase + wn * 48 + ni * 16 + q15;    // [0,384), p uniform per ni
        int p = n >> 7, c = n & 127;
        const float* bias = (p == 0) ? bq : (p == 1) ? bk : bv;
        float bval = bias[c] * ((p == 0) ? 0.08838834764831845f : 1.0f);
        #pragma unroll
        for (int mi = 0; mi < 2; ++mi) {
            int m0 = mt * 64 + wm * 32 + mi * 16 + g * 4;
            #pragma unroll
            for (int r = 0; r < 4; ++r) {
                unsigned short h = f2bf(acc[mi][ni][r] + bval);
                int m = m0 + r;
                if (p == 0) qb[(size_t)m * DH + c] = h;
                else if (p == 1) kb[(size_t)m * DH + c] = h;
                else vt[(size_t)((m >> 12) * 128 + c) * SEQ + (m & 4095)] = h;
            }
        }
    }
}

// ---------------------------------------------------------------------------
// attn pass 1: flash attention, QBLK=128 (8 waves x 16 q-rows), KVBLK=64,
// SPLITS=4, now DOUBLE-BUFFERED (T3-minimum 2-phase): issue next tile's
// global_load_lds DMA BEFORE computing the current tile; ONE barrier per
// iteration (its vmcnt drain waits on loads issued a full compute-phase
// earlier). LDS 80KB -> 2 blocks/CU (grid 512 = 2/CU exact). K/V linear
// LDS + XOR source swizzle; swapped QK^T; P via per-wave [kseg][q][8]
// LDS (linear PV read); cvt_pk pack; setprio on MFMA; defer-max THR=8.
// ---------------------------------------------------------------------------
__global__ __launch_bounds__(512) void attn_kernel(
    const unsigned short* __restrict__ qb,
    const unsigned short* __restrict__ kb,
    const unsigned short* __restrict__ vt,   // [4][128][4096]
    float* __restrict__ po,                  // [4 s][4 b][4096][128]
    float* __restrict__ pm, float* __restrict__ pl)  // [4 s][4 b][4096]
{
    __shared__ unsigned short K_lds[2][64 * 128];  // 2 x 16KB
    __shared__ unsigned short V_lds[2][128 * 64];  // 2 x 16KB (V^T)
    __shared__ unsigned short P_lds[8 * 1024];     // per wave: [8 kseg][16 q][8]
    const int tid = threadIdx.x;
    const int w = tid >> 6;                      // wave [0,8)
    const int lane = tid & 63;
    const int q15 = lane & 15, g = lane >> 4;
    const int xcd = blockIdx.x & 7, slot = blockIdx.x >> 3;   // slot [0,64)
    const int b = xcd >> 1;
    const int j = 31 - (slot >> 1);              // q-tile [0,32), long-first
    const int s = (slot & 1) * 2 + (xcd & 1);    // split [0,4)
    const int n = 2 * j + 2;                     // k-tiles for this q-tile
    const int lo = (n * s) >> 2, hi = (n * (s + 1)) >> 2;
    if (lo >= hi) return;                        // empty split (block-uniform)
    const int qbase = j * 128;
    const int wq0 = qbase + w * 16;              // wave's first q row
    const int qglob = wq0 + q15;

    bf16x8 qf[4];
    const unsigned short* qrow = qb + (size_t)(b * SEQ + qglob) * DH;
    #pragma unroll
    for (int kk = 0; kk < 4; ++kk) qf[kk] = *(const bf16x8*)(qrow + kk * 32 + g * 8);

    f32x4 o[8];
    #pragma unroll
    for (int f = 0; f < 8; ++f) o[f] = (f32x4){0.f, 0.f, 0.f, 0.f};
    float m_run = -60.0f, l_run = 0.f;           // finite sentinel

    const unsigned short* Kb = kb + (size_t)b * SEQ * DH;
    const unsigned short* Vb = vt + (size_t)b * 128 * SEQ;
    unsigned short* Pw = &P_lds[w * 1024];

    // staging lane mapping (computed once)
    const int krow0 = w * 4 + (lane >> 4);       // +i*32, [0,64)
    const int vrow0 = w * 8 + (lane >> 3);       // +i*64, [0,128)

    // ---- prologue: stage tile lo into buffer 0 ----
    {
        const unsigned short* Ksrc = Kb + (size_t)lo * 64 * DH;
        const unsigned short* Vsrc = Vb + lo * 64;
        #pragma unroll
        for (int i = 0; i < 2; ++i) {
            int krow = i * 32 + krow0;
            int kseg = (lane & 15) ^ (krow & 7);
            gload_lds16(Ksrc + (size_t)krow * DH + kseg * 8,
                        (char*)&K_lds[0][0] + i * 8192 + w * 1024);
            int vrow = i * 64 + vrow0;
            int vseg = (lane & 7) ^ (vrow & 7);
            gload_lds16(Vsrc + (size_t)vrow * SEQ + vseg * 8,
                        (char*)&V_lds[0][0] + i * 8192 + w * 1024);
        }
    }
    __syncthreads();

    int cur = 0;
    for (int kt = lo; kt < hi; ++kt) {
        // --- issue next tile's DMA into the other buffer (hidden below) ---
        if (kt + 1 < hi) {
            const unsigned short* Ksrc = Kb + (size_t)(kt + 1) * 64 * DH;
            const unsigned short* Vsrc = Vb + (kt + 1) * 64;
            #pragma unroll
            for (int i = 0; i < 2; ++i) {
                int krow = i * 32 + krow0;
                int kseg = (lane & 15) ^ (krow & 7);
                gload_lds16(Ksrc + (size_t)krow * DH + kseg * 8,
                            (char*)&K_lds[cur ^ 1][0] + i * 8192 + w * 1024);
                int vrow = i * 64 + vrow0;
                int vseg = (lane & 7) ^ (vrow & 7);
                gload_lds16(Vsrc + (size_t)vrow * SEQ + vseg * 8,
                            (char*)&V_lds[cur ^ 1][0] + i * 8192 + w * 1024);
            }
        }
        // --- S^T = K * Q^T (64 keys x 16 q), swizzled K reads ---
        f32x4 sf[4];
        __builtin_amdgcn_s_setprio(1);
        #pragma unroll
        for (int mt2 = 0; mt2 < 4; ++mt2) {
            f32x4 sa = (f32x4){0.f, 0.f, 0.f, 0.f};
            #pragma unroll
            for (int kk = 0; kk < 4; ++kk) {
                int seg = (kk * 4 + g) ^ (q15 & 7);
                bf16x8 kf = *(const bf16x8*)&K_lds[cur][(mt2 * 16 + q15) * 128 + seg * 8];
                sa = __builtin_amdgcn_mfma_f32_16x16x32_bf16(kf, qf[kk], sa, 0, 0, 0);
            }
            sf[mt2] = sa;
        }
        __builtin_amdgcn_s_setprio(0);
        // --- mask (boundary tiles only) + tile max ---
        float tmax = -__builtin_inff();
        if (kt * 64 + 63 > wq0) {                 // wave-uniform branch
            #pragma unroll
            for (int mt2 = 0; mt2 < 4; ++mt2)
                #pragma unroll
                for (int r = 0; r < 4; ++r) {
                    int kglob = kt * 64 + mt2 * 16 + g * 4 + r;
                    float v = (kglob <= qglob) ? sf[mt2][r] : -__builtin_inff();
                    sf[mt2][r] = v;
                    tmax = fmaxf(tmax, v);
                }
        } else {
            #pragma unroll
            for (int mt2 = 0; mt2 < 4; ++mt2)
                #pragma unroll
                for (int r = 0; r < 4; ++r) tmax = fmaxf(tmax, sf[mt2][r]);
        }
        tmax = fmaxf(tmax, __shfl_xor(tmax, 16));
        tmax = fmaxf(tmax, __shfl_xor(tmax, 32));
        // --- defer-max: rescale only when running max grows by > 8 ---
        if (!__all((tmax - m_run) <= 8.0f)) {
            float m_new = fmaxf(m_run, tmax);
            float c = __expf(m_run - m_new);
            float cr[4];
            #pragma unroll
            for (int r = 0; r < 4; ++r) cr[r] = __shfl(c, g * 4 + r);
            #pragma unroll
            for (int f = 0; f < 8; ++f)
                #pragma unroll
                for (int r = 0; r < 4; ++r) o[f][r] *= cr[r];
            l_run *= c;
            m_run = m_new;
        }
        // exp, then pack/write P FIRST (write latency hides under shfl reduce)
        #pragma unroll
        for (int mt2 = 0; mt2 < 4; ++mt2)
            #pragma unroll
            for (int r = 0; r < 4; ++r)
                sf[mt2][r] = __expf(sf[mt2][r] - m_run);
        #pragma unroll
        for (int mt2 = 0; mt2 < 4; ++mt2) {
            uint32_t p01 = cvt_pk_bf16(sf[mt2][0], sf[mt2][1]);
            uint32_t p23 = cvt_pk_bf16(sf[mt2][2], sf[mt2][3]);
            uint32_t* pd = (uint32_t*)(Pw + ((mt2 * 2 + (g >> 1)) * 16 + q15) * 8 + (g & 1) * 4);
            pd[0] = p01;
            pd[1] = p23;
        }
        float rsum = 0.f;
        #pragma unroll
        for (int mt2 = 0; mt2 < 4; ++mt2)
            #pragma unroll
            for (int r = 0; r < 4; ++r) rsum += sf[mt2][r];
        rsum += __shfl_xor(rsum, 16);
        rsum += __shfl_xor(rsum, 32);
        l_run += rsum;
        asm volatile("s_waitcnt lgkmcnt(0)" ::: "memory");
        // --- PV A-frag read: block kk2*4+g, row q15 -> base + lane*16 ---
        bf16x8 pf[2];
        #pragma unroll
        for (int kk2 = 0; kk2 < 2; ++kk2)
            pf[kk2] = *(const bf16x8*)&Pw[((kk2 * 4 + g) * 16 + q15) * 8];
        // --- PV: o[q][d] += P[q][k] * V[k][d], swizzled V reads ---
        __builtin_amdgcn_s_setprio(1);
        #pragma unroll
        for (int f = 0; f < 8; ++f) {
            #pragma unroll
            for (int kk2 = 0; kk2 < 2; ++kk2) {
                int seg = (kk2 * 4 + g) ^ (q15 & 7);
                bf16x8 vf = *(const bf16x8*)&V_lds[cur][(f * 16 + q15) * 64 + seg * 8];
                o[f] = __builtin_amdgcn_mfma_f32_16x16x32_bf16(pf[kk2], vf, o[f], 0, 0, 0);
            }
        }
        __builtin_amdgcn_s_setprio(0);
        // ONE barrier per iter: drains prefetch DMA (issued a compute-phase
        // ago) and guarantees all waves done reading buf[cur] before restage.
        __syncthreads();
        cur ^= 1;
    }
    float* pob = po + ((size_t)(s * NB + b) * SEQ + wq0) * DH;
    #pragma unroll
    for (int f = 0; f < 8; ++f)
        #pragma unroll
        for (int r = 0; r < 4; ++r)
            pob[(size_t)(g * 4 + r) * DH + f * 16 + q15] = o[f][r];
    if (g == 0) {
        size_t sidx = (size_t)(s * NB + b) * SEQ + wq0 + q15;
        pm[sidx] = m_run;
        pl[sidx] = l_run;
    }
}

// ---------------------------------------------------------------------------
// attn pass 2 (unchanged): combine the 4 split partials per row.
// ---------------------------------------------------------------------------
__global__ __launch_bounds__(256) void reduce_kernel(
    const float* __restrict__ po, const float* __restrict__ pm,
    const float* __restrict__ pl, float* __restrict__ out)
{
    int r = blockIdx.x * 8 + (threadIdx.x >> 5);     // row [0,16384)
    int d0 = (threadIdx.x & 31) * 4;
    int b = r >> 12, q = r & 4095;
    int n = 2 * (q >> 7) + 2;
    float ms[SPLITS];
    float M = -__builtin_inff();
    #pragma unroll
    for (int s = 0; s < SPLITS; ++s) {
        int lo = (n * s) >> 2, hi = (n * (s + 1)) >> 2;
        if (hi > lo) {
            ms[s] = pm[(size_t)(s * NB + b) * SEQ + q];
            M = fmaxf(M, ms[s]);
        } else ms[s] = -__builtin_inff();
    }
    float L = 0.f;
    f32x4 acc = (f32x4){0.f, 0.f, 0.f, 0.f};
    #pragma unroll
    for (int s = 0; s < SPLITS; ++s) {
        int lo = (n * s) >> 2, hi = (n * (s + 1)) >> 2;
        if (hi > lo) {
            float wgt = __expf(ms[s] - M);
            L += wgt * pl[(size_t)(s * NB + b) * SEQ + q];
            f32x4 p = *(const f32x4*)&po[((size_t)(s * NB + b) * SEQ + q) * DH + d0];
            acc += wgt * p;
        }
    }
    float inv = 1.0f / L;
    *(f32x4*)&out[((size_t)(b * SEQ) + q) * DH + d0] = acc * inv;
}

// ---------------------------------------------------------------------------
// Workspace layout (bytes):
//   po  @ 0         : 4*4*4096*128*4 = 33,554,432
//   Wt  @ 33554432  : 384*1024*2     =    786,432  | pm/pl alias after proj
//   qb  @ 34340864  : 16384*128*2    =  4,194,304
//   kb  @ 38535168  : 16384*128*2    =  4,194,304
//   vt  @ 42729472  : 4*128*4096*2   =  4,194,304
//   total ~46.9 MB
// ---------------------------------------------------------------------------
extern "C" void kernel_launch(void* const* d_in, const int* in_sizes, int n_in,
                              void* d_out, int out_size, void* d_ws, size_t ws_size,
                              hipStream_t stream)
{
    const float* x  = (const float*)d_in[0];
    const float* Wq = (const float*)d_in[1];
    const float* bq = (const float*)d_in[2];
    const float* Wk = (const float*)d_in[3];
    const float* bk = (const float*)d_in[4];
    const float* Wv = (const float*)d_in[5];
    const float* bv = (const float*)d_in[6];

    char* ws = (char*)d_ws;
    unsigned short* Wt = (unsigned short*)(ws + 33554432);
    unsigned short* qb = (unsigned short*)(ws + 34340864);
    unsigned short* kb = (unsigned short*)(ws + 38535168);
    unsigned short* vt = (unsigned short*)(ws + 42729472);
    float* po = (float*)(ws);
    float* pm = (float*)(ws + 33554432);        // aliases Wt (dead after proj)
    float* pl = (float*)(ws + 33554432 + 262144);

    prep_kernel<<<1536, 256, 0, stream>>>(Wq, Wk, Wv, Wt);
    proj_kernel<<<512, 512, 0, stream>>>(x, Wt, bq, bk, bv, qb, kb, vt);
    attn_kernel<<<512, 512, 0, stream>>>(qb, kb, vt, po, pm, pl);
    reduce_kernel<<<2048, 256, 0, stream>>>(po, pm, pl, (float*)d_out);
}